// Round 4
// baseline (130.156 us; speedup 1.0000x reference)
//
#include <hip/hip_runtime.h>
#include <math.h>

// KTVLoss: inputs out_l, out_r, input_i : (8,3,512,512) fp32. Output: 1 fp32 scalar.
//
// Sx = 10x10 box sum of |dI/dh| (502x503), Sy = box sum of |dI/dw| (503x502).
// Reference pairs them by FLAT index: Sx(i,j) with Sy(i,i+j) if i+j<502 else
// Sy(i+1,i+j-502). ratio = (SxL+SyL+SxR+SyR)/(SxI+SyI+1e-4), mean over 24*502*503.
// grad part (fp32): mean|GxL+GxR-GxI| + mean|GyL+GyR-GyI| over 24*511*512 each.
// norm part carries 1e-4 weight -> packed f16 (abs err ~1e-5; validated R4-R9).
//
// R14: R13 post-mortem identified the real bottleneck: the per-CU LDS pipe.
// 16 waves x ~30 LDS-pipe ops x ~5-6 cyc per-instruction overhead (m134)
// ~= 2500-2900 cyc of the ~5500-cyc superstep. VALU (per-SIMD) is only 40%.
// So this round halves LDS INSTRUCTION COUNT at constant bytes:
//  - rows ring split: rowsLR[col][2] (L,R interleaved) + rowsI[col].
//    ROWRD per row = 1 ds_read2_b64 (L,R @ j and j+1) + 1 ds_read2_b32
//    (I @ j,j+1): 4 DS instr/superstep vs 12. Staged with per-lane source
//    select (lane&1 ? pR : pL; dest stays linear) - still 3 gloads/row.
//  - awin re-layout [parity][col][rowpair]: A/B packs adjacent 8B slots ->
//    w0/w10/wT reads each merge A+B into ds_read2_b64 (6 reads -> 3);
//    the two SCANROW writes merge into one ds_write2_b64 (2 -> 1).
// DS ops/wave/superstep: 24 -> 12 (+6 gloads). Bytes, ring depths, vmcnt(6),
// RATIO/snap lags, LDS footprint (~70 KB, 2 blocks/CU) all unchanged.
//
// VGPR cap law (R4-R7): cap = 256/min_waves; (512,2) -> 128. Watch for spill.

namespace {

constexpr int H = 512, W = 512;
constexpr int CX = W - 10 + 1;   // 503 Sx cols (Sy has 503 rows)
constexpr int CY = W - 10;       // 502 Sy cols
constexpr int RB = 24;           // Sx rows per band
constexpr int NBANDS = (CY + RB - 1) / RB;   // 21
constexpr int NIMG = 24;
constexpr int NBLOCKS = NIMG * NBANDS;       // 504

typedef __fp16 h2 __attribute__((ext_vector_type(2)));

__device__ __forceinline__ int h2i(h2 v) { int r; __builtin_memcpy(&r, &v, 4); return r; }
__device__ __forceinline__ h2 i2h(int v) { h2 r; __builtin_memcpy(&r, &v, 4); return r; }

template <int C, int RM>
__device__ __forceinline__ int dppmov(int v) {
  return __builtin_amdgcn_update_dpp(0, v, C, RM, 0xf, true);
}
// full 64-lane inclusive prefix sum of a f16x2 pack (pure VALU)
__device__ __forceinline__ h2 scan64(h2 v) {
  v += i2h(dppmov<0x111, 0xf>(h2i(v)));  // row_shr:1
  v += i2h(dppmov<0x112, 0xf>(h2i(v)));  // row_shr:2
  v += i2h(dppmov<0x114, 0xf>(h2i(v)));  // row_shr:4
  v += i2h(dppmov<0x118, 0xf>(h2i(v)));  // row_shr:8
  v += i2h(dppmov<0x142, 0xa>(h2i(v)));  // row_bcast15 -> rows 1,3
  v += i2h(dppmov<0x143, 0xc>(h2i(v)));  // row_bcast31 -> rows 2,3
  return v;
}

// async global->LDS, 4 bytes/lane, dest = wave-uniform base + lane*4,
// global source address is PER-LANE (enables the channel-interleave stage)
__device__ __forceinline__ void gload(const float* g, float* l) {
  __builtin_amdgcn_global_load_lds((const __attribute__((address_space(1))) void*)g,
                                   (__attribute__((address_space(3))) void*)l, 4, 0, 0);
}

// barrier with COUNTED vmcnt(6): lgkmcnt(0) for LDS visibility; the current
// superstep's 6 staging loads stay in flight across the barrier (never 0).
// encoding: vmcnt[3:0]=6, exp[6:4]=7(max), lgkm[11:8]=0, vmcnt[15:14]=0.
__device__ __forceinline__ void kbarrier_vm() {
  __builtin_amdgcn_sched_barrier(0);
  __builtin_amdgcn_s_waitcnt(0x0076);
  __builtin_amdgcn_s_barrier();
  __builtin_amdgcn_sched_barrier(0);
}

}  // namespace

// ---- stage row Q (clamped): 2 LR-interleaved calls + 1 linear I call ----
// pLR = (lane&1 ? pR : pL) + wv*64 + (lane>>1)  (precomputed per thread)
#define STAGE(Q)                                                                  \
  {                                                                               \
    constexpr int q_ = ((Q) > 33) ? 33 : (Q);                                     \
    int grow = i0 + q_;                                                           \
    if (grow > H - 1) grow = H - 1; /* last band: re-reads row 511, masked */     \
    const int gg = grow * W;                                                      \
    gload(pLR + gg,      &rowsLR[q_ % 6][wv * 64][0]);                            \
    gload(pLR + gg + 32, &rowsLR[q_ % 6][wv * 64 + 32][0]);                       \
    gload(pI + gg + j,   &rowsI[q_ % 6][wv * 64]);                                \
  }

#define ROWRD_DECL(P)                                                             \
  float xV##P##L = 0.f, xV##P##R = 0.f, xV##P##I = 0.f;                           \
  float xN##P##L = 0.f, xN##P##R = 0.f, xN##P##I = 0.f;

// ---- read row S cols j, j+1: 1 ds_read2_b64 (L,R) + 1 ds_read2_b32 (I) ----
#define ROWRD(S, P)                                                               \
  {                                                                               \
    constexpr int sl = (S) % 6;                                                   \
    const float2 va = *(const float2*)&rowsLR[sl][j][0];                          \
    const float2 vb = *(const float2*)&rowsLR[sl][j + 1][0];                      \
    xV##P##L = va.x; xV##P##R = va.y;                                             \
    xN##P##L = vb.x; xN##P##R = vb.y;                                             \
    xV##P##I = rowsI[sl][j]; xN##P##I = rowsI[sl][j + 1];                         \
  }

// ---- per-row scan: gradients, pack, DPP scan, prefix pack -> pk (reg) ----
#define SCANROW(S, P)                                                             \
  {                                                                               \
    constexpr int s_ = (S);                                                       \
    const int r = i0 + s_;                                                        \
    const float xl = xV##P##L, xr = xV##P##R, xi = xV##P##I;                      \
    const float gyl = xN##P##L - xl, gyr = xN##P##R - xr, gyi = xN##P##I - xi;    \
    const float gxl = xl - prevL, gxr = xr - prevR, gxi = xi - prevI;             \
    prevL = xl; prevR = xr; prevI = xi;                                           \
    if (r < gyEnd && j < W - 1) accGY += fabsf(gyl + gyr - gyi);                  \
    if (s_ > 0 && (r - 1) < gxEnd) accGX += fabsf(gxl + gxr - gxi);               \
    float yn = fabsf(gyl) + fabsf(gyr), yd = fabsf(gyi);                          \
    float xn = fabsf(gxl) + fabsf(gxr), xd = fabsf(gxi);                          \
    if (j == W - 1) { yn = 0.f; yd = 0.f; }                                       \
    if (r >= H) { yn = 0.f; yd = 0.f; xn = 0.f; xd = 0.f; }                       \
    const h2 Y = __builtin_amdgcn_cvt_pkrtz(yn, yd);                              \
    h2 X = (h2)(__fp16)0;                                                         \
    if (s_ != 0) X = __builtin_amdgcn_cvt_pkrtz(xn, xd);                          \
    const h2 AY = scan64(Y), AX = scan64(X);                                      \
    pk##P = make_int2(h2i(AY), h2i(AX));                                          \
  }

// ---- window combine + vertical ring for row TT (set P); awin reads were ----
// ---- issued at superstep top, one barrier after they were written.      ----
#define PATCHRING(TT, P)                                                          \
  {                                                                               \
    constexpr int t_ = (TT);                                                      \
    constexpr int hs = (t_ + 20) % 10;                                            \
    h2 hh = i2h(w10##P.x), hx = i2h(w10##P.y);                                    \
    if (lane != 0) { hh -= i2h(w0##P.x); hx -= i2h(w0##P.y); }                    \
    if (patch) { hh += i2h(wT##P.x); hx += i2h(wT##P.y); }                        \
    runY += hh - histY[hs]; histY[hs] = hh;                                       \
    runX += hx - histX[hs]; histX[hs] = hx;                                       \
    snap##P = runX;                                                               \
    if (t_ >= 9) {                                                                \
      const int iY = (i0 + t_) - 9;                                               \
      if (iY <= sxEnd && j < CY) syring[iY & 7][j] = h2i(runY);                   \
    }                                                                             \
  }

// ---- ratio for Sx row U: issue syring read at superstep top ... ----
#define RATIO_RD(U, P)                                                            \
  int syrd##P = 0, uok##P = 0;                                                    \
  {                                                                               \
    constexpr int u_ = (U);                                                       \
    if (u_ >= 0) {                                                                \
      const int iX = i0 + u_;                                                     \
      if (iX < sxEnd && j < CX) {                                                 \
        int jy = iX + j, rw = iX;                                                 \
        if (jy >= CY) { jy -= CY; ++rw; }                                         \
        syrd##P = syring[rw & 7][jy];                                             \
        uok##P = 1;                                                               \
      }                                                                           \
    }                                                                             \
  }

// ---- ... consume it (with the previous superstep's snap) later ----
#define RATIO_FIN(P)                                                              \
  if (uok##P) {                                                                   \
    const h2 sy = i2h(syrd##P);                                                   \
    const float num = (float)snap##P.x + (float)sy.x;                             \
    const float den = (float)snap##P.y + (float)sy.y + 1e-4f;                     \
    accN += num * __builtin_amdgcn_rcpf(den);                                     \
  }

// ---- 2-row superstep: ALL LDS reads at top (paired A+B via read2), stage, ----
// ---- ratio / window-combine / scans, paired awin write, counted barrier.  ----
#define SUPER(T_)                                                                 \
  {                                                                               \
    constexpr int tT = (T_);                                                      \
    constexpr int TP = tT & 1;                                                    \
    constexpr int a0 = 2 * tT, a1 = a0 + 1;                                       \
    RATIO_RD(a0 - 14, A)                                                          \
    RATIO_RD(a0 - 13, B)                                                          \
    int2 w0A = make_int2(0, 0), w10A = w0A, wTA = w0A;                            \
    int2 w0B = w0A, w10B = w0A, wTB = w0A;                                        \
    if (tT >= 1) { /* prefix packs of rows a0-2 (A), a0-1 (B): merged reads */    \
      w0A  = awin[TP ^ 1][j][0];       w0B  = awin[TP ^ 1][j][1];                 \
      w10A = awin[TP ^ 1][j + 10][0];  w10B = awin[TP ^ 1][j + 10][1];            \
      wTA  = awin[TP ^ 1][wtop][0];    wTB  = awin[TP ^ 1][wtop][1];              \
    }                                                                             \
    ROWRD_DECL(A) ROWRD_DECL(B)                                                   \
    if (a0 <= 33) ROWRD(a0, A)                                                    \
    if (a1 <= 33) ROWRD(a1, B)                                                    \
    STAGE(a0 + 4) STAGE(a0 + 5)                                                   \
    RATIO_FIN(A) RATIO_FIN(B)                                                     \
    if (tT >= 1 && (a0 - 2) <= 33) PATCHRING(a0 - 2, A)                           \
    if (tT >= 1 && (a0 - 1) <= 33) PATCHRING(a0 - 1, B)                           \
    int2 pkA, pkB;                                                                \
    if (a0 <= 33) {                                                               \
      SCANROW(a0, A)                                                              \
      SCANROW(a1, B)                                                              \
      awin[TP][j + 1][0] = pkA;  /* adjacent: merges to ds_write2_b64 */          \
      awin[TP][j + 1][1] = pkB;                                                   \
    }                                                                             \
    kbarrier_vm();                                                                \
  }

__global__ __launch_bounds__(512, 2) void ktv_main(const float* __restrict__ L,
                                                   const float* __restrict__ R,
                                                   const float* __restrict__ I,
                                                   double* __restrict__ partial) {
  const int blk = blockIdx.x;
  const int img = blk / NBANDS;
  const int band = blk % NBANDS;
  const int i0 = band * RB;
  const int j = threadIdx.x;  // column
  const int lane = j & 63;
  const int wv = j >> 6;
  const int wtop = (wv + 1) << 6;            // awin slot holding own wave's total
  const bool patch = (lane >= 55) && (wv < 7);  // window crosses into next wave

  const bool lastb = (band == NBANDS - 1);
  const int gyEnd = lastb ? H : (i0 + RB);        // Gy rows owned: [i0, gyEnd)
  const int gxEnd = lastb ? (H - 1) : (i0 + RB);  // Gx rows owned: [i0, gxEnd)
  const int sxEnd = lastb ? CY : (i0 + RB);       // Sx rows owned: [i0, sxEnd)

  const size_t base = (size_t)img * (H * W);
  const float* pL = L + base;
  const float* pR = R + base;
  const float* pI = I + base;
  // per-thread LR staging source: channel = lane&1 (L or R), col = wv*64+(lane>>1)
  const float* pLR = ((lane & 1) ? pR : pL) + (wv * 64 + (lane >> 1));

  __shared__ float rowsLR[6][513][2];  // staged L,R rows interleaved (+pad col)
  __shared__ float rowsI[6][513];      // staged I rows (+pad col)
  __shared__ int syring[8][CY];        // completed Sy rows (f16x2 n,d), depth-8 ring
  __shared__ int2 awin[2][522][2];     // prefix packs: [superstep parity][col][row parity]
                                       // slot k = prefix through col k-1; [64w] = T_{w-1}
  __shared__ float redN[8], redGX[8], redGY[8];

  h2 histY[10], histX[10];
#pragma unroll
  for (int t = 0; t < 10; ++t) { histY[t] = (h2)(__fp16)0; histX[t] = (h2)(__fp16)0; }
  h2 runY = (h2)(__fp16)0, runX = (h2)(__fp16)0;
  h2 snapA = (h2)(__fp16)0, snapB = snapA;
  float accN = 0.f, accGX = 0.f, accGY = 0.f;
  float prevL = 0.f, prevR = 0.f, prevI = 0.f;

  // prologue: stage rows 0..3 (12 loads); zero the col-512 pad entries
  STAGE(0) STAGE(1) STAGE(2) STAGE(3)
  if (j < 12) rowsLR[j >> 1][512][j & 1] = 0.f;
  else if (j < 18) rowsI[j - 12][512] = 0.f;
  __builtin_amdgcn_sched_barrier(0);
  __builtin_amdgcn_s_waitcnt(0x0076);  // vmcnt(6): rows 0,1 landed; lgkm(0)
  __builtin_amdgcn_s_barrier();
  __builtin_amdgcn_sched_barrier(0);

  // 19 supersteps: scans T=0..16 (rows 0..33), PATCH through T=17, RATIO T=7..18
  SUPER(0)  SUPER(1)  SUPER(2)  SUPER(3)  SUPER(4)  SUPER(5)
  SUPER(6)  SUPER(7)  SUPER(8)  SUPER(9)  SUPER(10) SUPER(11)
  SUPER(12) SUPER(13) SUPER(14) SUPER(15) SUPER(16) SUPER(17)
  SUPER(18)

  // block reduction
#pragma unroll
  for (int o2 = 32; o2 > 0; o2 >>= 1) {
    accN  += __shfl_down(accN, o2);
    accGX += __shfl_down(accGX, o2);
    accGY += __shfl_down(accGY, o2);
  }
  if (lane == 0) { redN[wv] = accN; redGX[wv] = accGX; redGY[wv] = accGY; }
  __syncthreads();
  if (j == 0) {
    float n = 0.f, gx = 0.f, gy = 0.f;
#pragma unroll
    for (int w2 = 0; w2 < 8; ++w2) { n += redN[w2]; gx += redGX[w2]; gy += redGY[w2]; }
    double* p = partial + (size_t)blk * 3;
    p[0] = (double)n; p[1] = (double)gx; p[2] = (double)gy;
  }
}

__global__ __launch_bounds__(64) void ktv_reduce(const double* __restrict__ partial,
                                                 float* __restrict__ out) {
  double n = 0.0, gx = 0.0, gy = 0.0;
  for (int i = threadIdx.x; i < NBLOCKS; i += 64) {
    const double* p = partial + (size_t)i * 3;
    n += p[0]; gx += p[1]; gy += p[2];
  }
#pragma unroll
  for (int o2 = 32; o2 > 0; o2 >>= 1) {
    n  += __shfl_down(n, o2);
    gx += __shfl_down(gx, o2);
    gy += __shfl_down(gy, o2);
  }
  if (threadIdx.x == 0) {
    const double norm_loss = n / 6060144.0;          // 24*502*503
    const double grad_loss = (gx + gy) / 6279168.0;  // 24*511*512
    out[0] = (float)(1e-4 * norm_loss + grad_loss);
  }
}

extern "C" void kernel_launch(void* const* d_in, const int* in_sizes, int n_in,
                              void* d_out, int out_size, void* d_ws, size_t ws_size,
                              hipStream_t stream) {
  (void)in_sizes; (void)n_in; (void)out_size; (void)ws_size;
  const float* L = (const float*)d_in[0];
  const float* R = (const float*)d_in[1];
  const float* I = (const float*)d_in[2];
  double* partial = (double*)d_ws;   // NBLOCKS*3 doubles = 12096 B
  float* out = (float*)d_out;

  hipLaunchKernelGGL(ktv_main, dim3(NBLOCKS), dim3(512), 0, stream, L, R, I, partial);
  hipLaunchKernelGGL(ktv_reduce, dim3(1), dim3(64), 0, stream, partial, out);
}